// Round 2
// baseline (713.885 us; speedup 1.0000x reference)
//
#include <hip/hip_runtime.h>
#include <math.h>

#define B_ROWS 8192
#define P_KEYS 2048
#define D_DIM  768
#define L_LEN  5
#define K_SEL  5
#define EPSV   1e-8f

#define NSPLIT 4
#define COLS_PER_SPLIT (P_KEYS / NSPLIT)   // 512
#define ROW_TILE 64
#define COL_TILE 64
#define KB 16

// sorted ascending (v[0] best). Tie-break: lower index wins (jax top_k semantics).
__device__ inline void insert5(float (&v)[K_SEL], int (&ix)[K_SEL], float nv, int ni) {
    if (nv < v[K_SEL-1] || (nv == v[K_SEL-1] && ni < ix[K_SEL-1])) {
        v[K_SEL-1] = nv; ix[K_SEL-1] = ni;
        #pragma unroll
        for (int j = K_SEL-1; j > 0; --j) {
            bool sw = (v[j] < v[j-1]) || (v[j] == v[j-1] && ix[j] < ix[j-1]);
            if (sw) {
                float tv = v[j]; v[j] = v[j-1]; v[j-1] = tv;
                int   ti = ix[j]; ix[j] = ix[j-1]; ix[j-1] = ti;
            }
        }
    }
}

// One wave (64 lanes) per row. waves [0, P_KEYS): normalize pool_key -> kn.
// waves [P_KEYS, P_KEYS+B_ROWS): compute 1/max(||x||, eps) -> inv_x.
__global__ __launch_bounds__(256)
void norm_kernel(const float* __restrict__ x, const float* __restrict__ pk,
                 float* __restrict__ kn, float* __restrict__ inv_x) {
    int wave = (blockIdx.x * blockDim.x + threadIdx.x) >> 6;
    int lane = threadIdx.x & 63;
    bool is_key = (wave < P_KEYS);
    int row = is_key ? wave : wave - P_KEYS;
    const float* src = is_key ? (pk + (size_t)row * D_DIM) : (x + (size_t)row * D_DIM);

    const float4* s4 = (const float4*)src;
    float4 v[3];
    float s = 0.f;
    #pragma unroll
    for (int i = 0; i < 3; ++i) {
        v[i] = s4[lane + 64 * i];
        s += v[i].x * v[i].x + v[i].y * v[i].y + v[i].z * v[i].z + v[i].w * v[i].w;
    }
    #pragma unroll
    for (int off = 32; off; off >>= 1) s += __shfl_xor(s, off, 64);
    float inv = 1.0f / fmaxf(sqrtf(s), EPSV);

    if (is_key) {
        float4* d4 = (float4*)(kn + (size_t)row * D_DIM);
        #pragma unroll
        for (int i = 0; i < 3; ++i) {
            float4 w = v[i];
            w.x *= inv; w.y *= inv; w.z *= inv; w.w *= inv;
            d4[lane + 64 * i] = w;
        }
    } else {
        if (lane == 0) inv_x[row] = inv;
    }
}

// Fused fp32 GEMM (dist = 1 - x_hat . k_hat) + per-row running top-5.
// grid = (NSPLIT, B_ROWS/ROW_TILE). Block 256 = 16x16 threads, 4x4 microtile.
__global__ __launch_bounds__(256)
void gemm_top5_kernel(const float* __restrict__ x, const float* __restrict__ kn,
                      const float* __restrict__ inv_x,
                      float* __restrict__ cand_val, int* __restrict__ cand_idx) {
    const int split = blockIdx.x;
    const int rb    = blockIdx.y;
    const int row0  = rb * ROW_TILE;
    const int col_base = split * COLS_PER_SPLIT;

    __shared__ float As[KB][ROW_TILE + 4];   // k-major, +4 pad keeps float4 alignment
    __shared__ float Bs[KB][COL_TILE + 4];
    __shared__ float mval[ROW_TILE][16][K_SEL];
    __shared__ int   midx[ROW_TILE][16][K_SEL];

    const int tid = threadIdx.x;
    const int tx = tid & 15, ty = tid >> 4;

    float tv[4][K_SEL]; int tix[4][K_SEL];
    #pragma unroll
    for (int i = 0; i < 4; ++i)
        #pragma unroll
        for (int j = 0; j < K_SEL; ++j) { tv[i][j] = 3.0e38f; tix[i][j] = 0x7fffffff; }

    const int s_row = tid >> 2;          // 0..63
    const int s_k4  = (tid & 3) * 4;     // 0,4,8,12
    const float invn = inv_x[row0 + s_row];

    for (int ct = 0; ct < COLS_PER_SPLIT / COL_TILE; ++ct) {
        const int c0 = col_base + ct * COL_TILE;
        float acc[4][4] = {};

        for (int k0 = 0; k0 < D_DIM; k0 += KB) {
            __syncthreads();
            float4 av = *(const float4*)(x + (size_t)(row0 + s_row) * D_DIM + k0 + s_k4);
            As[s_k4 + 0][s_row] = av.x * invn;
            As[s_k4 + 1][s_row] = av.y * invn;
            As[s_k4 + 2][s_row] = av.z * invn;
            As[s_k4 + 3][s_row] = av.w * invn;
            float4 bv = *(const float4*)(kn + (size_t)(c0 + s_row) * D_DIM + k0 + s_k4);
            Bs[s_k4 + 0][s_row] = bv.x;
            Bs[s_k4 + 1][s_row] = bv.y;
            Bs[s_k4 + 2][s_row] = bv.z;
            Bs[s_k4 + 3][s_row] = bv.w;
            __syncthreads();

            #pragma unroll
            for (int k = 0; k < KB; ++k) {
                float4 a4 = *(const float4*)&As[k][ty * 4];
                float4 b4 = *(const float4*)&Bs[k][tx * 4];
                acc[0][0] += a4.x * b4.x; acc[0][1] += a4.x * b4.y;
                acc[0][2] += a4.x * b4.z; acc[0][3] += a4.x * b4.w;
                acc[1][0] += a4.y * b4.x; acc[1][1] += a4.y * b4.y;
                acc[1][2] += a4.y * b4.z; acc[1][3] += a4.y * b4.w;
                acc[2][0] += a4.z * b4.x; acc[2][1] += a4.z * b4.y;
                acc[2][2] += a4.z * b4.z; acc[2][3] += a4.z * b4.w;
                acc[3][0] += a4.w * b4.x; acc[3][1] += a4.w * b4.y;
                acc[3][2] += a4.w * b4.z; acc[3][3] += a4.w * b4.w;
            }
        }

        #pragma unroll
        for (int i = 0; i < 4; ++i)
            #pragma unroll
            for (int j = 0; j < 4; ++j) {
                float dv = 1.0f - acc[i][j];
                int ci = c0 + tx * 4 + j;
                insert5(tv[i], tix[i], dv, ci);
            }
    }

    // merge the 16 column-threads per row
    #pragma unroll
    for (int i = 0; i < 4; ++i) {
        int r = ty * 4 + i;
        #pragma unroll
        for (int j = 0; j < K_SEL; ++j) { mval[r][tx][j] = tv[i][j]; midx[r][tx][j] = tix[i][j]; }
    }
    __syncthreads();
    if (tid < ROW_TILE) {
        float fv[K_SEL]; int fi[K_SEL];
        #pragma unroll
        for (int j = 0; j < K_SEL; ++j) { fv[j] = 3.0e38f; fi[j] = 0x7fffffff; }
        for (int t = 0; t < 16; ++t)
            for (int j = 0; j < K_SEL; ++j) insert5(fv, fi, mval[tid][t][j], midx[tid][t][j]);
        int grow = row0 + tid;
        #pragma unroll
        for (int j = 0; j < K_SEL; ++j) {
            cand_val[((size_t)grow * NSPLIT + split) * K_SEL + j] = fv[j];
            cand_idx[((size_t)grow * NSPLIT + split) * K_SEL + j] = fi[j];
        }
    }
}

__global__ __launch_bounds__(256)
void merge_kernel(const float* __restrict__ cand_val, const int* __restrict__ cand_idx,
                  float* __restrict__ out_dist, int* __restrict__ final_idx) {
    int row = blockIdx.x * blockDim.x + threadIdx.x;
    if (row >= B_ROWS) return;
    float fv[K_SEL]; int fi[K_SEL];
    #pragma unroll
    for (int j = 0; j < K_SEL; ++j) { fv[j] = 3.0e38f; fi[j] = 0x7fffffff; }
    for (int t = 0; t < NSPLIT * K_SEL; ++t)
        insert5(fv, fi, cand_val[(size_t)row * NSPLIT * K_SEL + t],
                        cand_idx[(size_t)row * NSPLIT * K_SEL + t]);
    #pragma unroll
    for (int j = 0; j < K_SEL; ++j) {
        out_dist[(size_t)row * K_SEL + j] = fv[j];
        final_idx[(size_t)row * K_SEL + j] = fi[j];
    }
}

// one block per (b, s): copy prompts[idx] (5*768 floats = 960 float4) to output
__global__ __launch_bounds__(256)
void gather_kernel(const float* __restrict__ prompts, const int* __restrict__ final_idx,
                   float* __restrict__ out1) {
    int bs = blockIdx.x;                 // 0 .. B_ROWS*K_SEL-1
    int p = final_idx[bs];
    const float4* src = (const float4*)(prompts + (size_t)p * (L_LEN * D_DIM));
    float4* dst = (float4*)(out1 + (size_t)bs * (L_LEN * D_DIM));
    const int n4 = (L_LEN * D_DIM) / 4;  // 960
    for (int i = threadIdx.x; i < n4; i += blockDim.x) dst[i] = src[i];
}

extern "C" void kernel_launch(void* const* d_in, const int* in_sizes, int n_in,
                              void* d_out, int out_size, void* d_ws, size_t ws_size,
                              hipStream_t stream) {
    const float* x       = (const float*)d_in[0];   // [8192, 768]
    const float* pk      = (const float*)d_in[1];   // [2048, 768]
    const float* prompts = (const float*)d_in[2];   // [2048, 5, 768]

    float* out_dist = (float*)d_out;                       // [8192, 5]
    float* out_pr   = (float*)d_out + (size_t)B_ROWS * K_SEL; // [8192, 5, 5, 768]

    char* ws = (char*)d_ws;
    float* kn       = (float*)(ws);                              // 6,291,456 B
    float* inv_x    = (float*)(ws + 6291456);                    //    32,768 B
    float* cand_val = (float*)(ws + 6291456 + 32768);            //   655,360 B
    int*   cand_idx = (int*)  (ws + 6291456 + 32768 + 655360);   //   655,360 B
    int*   final_ix = (int*)  (ws + 6291456 + 32768 + 2*655360); //   163,840 B

    // 1) norms: (P_KEYS + B_ROWS) waves, 4 waves/block
    {
        int waves = P_KEYS + B_ROWS;
        norm_kernel<<<waves / 4, 256, 0, stream>>>(x, pk, kn, inv_x);
    }
    // 2) fused GEMM + per-split top5
    {
        dim3 grid(NSPLIT, B_ROWS / ROW_TILE);
        gemm_top5_kernel<<<grid, 256, 0, stream>>>(x, kn, inv_x, cand_val, cand_idx);
    }
    // 3) cross-split merge
    merge_kernel<<<B_ROWS / 256, 256, 0, stream>>>(cand_val, cand_idx, out_dist, final_ix);
    // 4) gather prompts
    gather_kernel<<<B_ROWS * K_SEL, 256, 0, stream>>>(prompts, final_ix, out_pr);
}